// Round 11
// baseline (148.347 us; speedup 1.0000x reference)
//
#include <hip/hip_runtime.h>
#include <hip/hip_bf16.h>

#define LOG2E 1.4426950408889634f
#define LN2   0.6931471805599453f

typedef __attribute__((ext_vector_type(8))) short bf16x8;
typedef __attribute__((ext_vector_type(4))) float f32x4;

static __device__ __forceinline__ short f2bf(float f) {
  __hip_bfloat16 h = __float2bfloat16(f);
  return *reinterpret_cast<short*>(&h);
}

// ---------------------------------------------------------------------------
// wprep: pack W (f32 [256][64]) into per-lane MFMA B-fragments (bf16).
// wfrag[enc][f][lane][j], f=nsub*8+ks; elem = W[ks*32+(lane>>4)*8+j][nsub*16+(lane&15)]
// ---------------------------------------------------------------------------
__global__ __launch_bounds__(256) void wprep_kernel(
    const float* __restrict__ Ww, const float* __restrict__ Wi,
    ushort* __restrict__ wfrag)
{
  int id = blockIdx.x * 256 + threadIdx.x;       // 0..4095
  if (id >= 4096) return;
  int enc  = id >> 11;
  int f    = (id >> 6) & 31;
  int l    = id & 63;
  int nsub = f >> 3, ks = f & 7;
  const float* __restrict__ W = enc ? Wi : Ww;
  int n  = nsub * 16 + (l & 15);
  int k0 = ks * 32 + (l >> 4) * 8;
  ushort* dst = wfrag + ((size_t)(enc * 32 + f) * 64 + l) * 8;
#pragma unroll
  for (int j = 0; j < 8; ++j)
    dst[j] = (ushort)f2bf(W[(size_t)(k0 + j) * 64 + n]);
}

// ---------------------------------------------------------------------------
// enc_simple: ONE 16-row strip per block, plain HIP only.
// Stage strip (16KB) to LDS with vectorized loads + store-side XOR swizzle
// (read = 2-way conflict = free; write = full-row permutation = conflict-
// free). One __syncthreads. Wave w computes 16-col slice nsub=w via 8 MFMAs.
// No inline asm, no global_load_lds, no counted vmcnt, no loops.
// Latency hidden by block-level parallelism (grid 6250x2, ~4 blocks/CU).
// Requires M%16==0.
// ---------------------------------------------------------------------------
__global__ __launch_bounds__(256) void enc_simple_kernel(
    const float* __restrict__ x0, const float* __restrict__ b0,
    const float* __restrict__ x1, const float* __restrict__ b1,
    const ushort* __restrict__ wfrag, float* __restrict__ out, int M)
{
  __shared__ f32x4 xt[1024];                      // 16 rows x 64 chunks (16KB)

  const int enc = blockIdx.y;
  const float* __restrict__ x   = enc ? x1 : x0;
  const float* __restrict__ bia = enc ? b1 : b0;
  float* __restrict__ o = out + (size_t)enc * (size_t)M * 64u;

  const int t    = threadIdx.x;
  const int lane = t & 63;
  const int wid  = t >> 6;
  const int rsel = lane & 15;                     // A row / C col within tile
  const int kgrp = lane >> 4;                     // k-group / C row-group
  const int sw   = rsel & 7;
  const int strip = blockIdx.x;

  // W fragments + bias first (L2-hot; overlaps the x staging below)
  bf16x8 wf[8];
#pragma unroll
  for (int ks = 0; ks < 8; ++ks)
    wf[ks] = *(const bf16x8*)(wfrag +
        ((size_t)((enc * 32 + wid * 8 + ks) * 64 + lane)) * 8);
  float bv = bia[wid * 16 + rsel];

  // stage strip: 4 passes x 256 threads x 16B = 16KB, coalesced 1KB/wave/instr
  const f32x4* __restrict__ xs = (const f32x4*)(x + (size_t)strip * 4096u);
#pragma unroll
  for (int p = 0; p < 4; ++p) {
    int idx = p * 256 + t;                        // 0..1023
    int row = idx >> 6, ch = idx & 63;
    xt[row * 64 + (ch ^ (row & 7))] = xs[idx];    // swizzled store
  }
  __syncthreads();

  // fragments + MFMA: A[rsel][ks*32+kgrp*8 .. +7] = chunks c0=ks*8+kgrp*2, +1
  f32x4 acc = f32x4{0.f, 0.f, 0.f, 0.f};
#pragma unroll
  for (int ks = 0; ks < 8; ++ks) {
    int c0 = ks * 8 + kgrp * 2;
    f32x4 lo = xt[rsel * 64 + ((c0    ) ^ sw)];
    f32x4 hi = xt[rsel * 64 + ((c0 + 1) ^ sw)];
    bf16x8 a;
    a[0] = f2bf(lo.x); a[1] = f2bf(lo.y); a[2] = f2bf(lo.z); a[3] = f2bf(lo.w);
    a[4] = f2bf(hi.x); a[5] = f2bf(hi.y); a[6] = f2bf(hi.z); a[7] = f2bf(hi.w);
    acc = __builtin_amdgcn_mfma_f32_16x16x32_bf16(a, wf[ks], acc, 0, 0, 0);
  }

  // epilogue: bias + leaky relu; C/D: col=rsel, row=kgrp*4+r
  const int crow = strip * 16 + kgrp * 4;
  float* orow = o + (size_t)crow * 64u + wid * 16 + rsel;
#pragma unroll
  for (int r = 0; r < 4; ++r) {
    float v = acc[r] + bv;
    v = fmaxf(v, 0.01f * v);
    orow[r * 64] = v;
  }
}

// ---------------------------------------------------------------------------
// Kernel B: pw = xw @ W_edge[0:64,:] (+b) ; pi = xi @ W_edge[64:128,:]
// rows padded to 16 floats (single-128B-line gathers); b_edge folded in.
// ---------------------------------------------------------------------------
__global__ __launch_bounds__(256) void proj_kernel(
    const float* __restrict__ feats, const float* __restrict__ W_edge,
    const float* __restrict__ b_edge, float* __restrict__ ws, int M)
{
  const int enc = blockIdx.y;
  int row = blockIdx.x * 256 + threadIdx.x;
  if (row >= M) return;
  const float4* __restrict__ f4 =
      (const float4*)(feats + ((size_t)enc * M + row) * 64u);
  const float* __restrict__ W2 = W_edge + enc * 640;   // 64 rows x 10 cols

  float acc[10];
#pragma unroll
  for (int k = 0; k < 10; ++k) acc[k] = enc ? 0.f : b_edge[k];

#pragma unroll 4
  for (int n4 = 0; n4 < 16; ++n4) {
    float4 xv = f4[n4];
    const float* w = W2 + n4 * 40;
#pragma unroll
    for (int k = 0; k < 10; ++k) acc[k] = fmaf(xv.x, w[k],      acc[k]);
#pragma unroll
    for (int k = 0; k < 10; ++k) acc[k] = fmaf(xv.y, w[10 + k], acc[k]);
#pragma unroll
    for (int k = 0; k < 10; ++k) acc[k] = fmaf(xv.z, w[20 + k], acc[k]);
#pragma unroll
    for (int k = 0; k < 10; ++k) acc[k] = fmaf(xv.w, w[30 + k], acc[k]);
  }

  float* orow = ws + ((size_t)enc * M + row) * 16u;
#pragma unroll
  for (int k = 0; k < 10; ++k) orow[k] = acc[k];
}

// ---------------------------------------------------------------------------
// Kernel C: logits[e] = pw[e0] + pi[e1]; log_softmax; dense float4 stores.
// ---------------------------------------------------------------------------
__global__ __launch_bounds__(256) void edge_kernel(
    const int* __restrict__ ei, const float* __restrict__ ws,
    float* __restrict__ out, int E, int M)
{
  __shared__ float sm[2560];
  long e = (long)blockIdx.x * 256 + threadIdx.x;
  float l[10];
#pragma unroll
  for (int k = 0; k < 10; ++k) l[k] = 0.f;

  if (e < E) {
    int e0 = ei[e];
    int e1 = ei[E + e];
    const float4* pw = (const float4*)ws + (size_t)e0 * 4u;
    const float4* pi = (const float4*)ws + ((size_t)M + e1) * 4u;
    float4 a0 = pw[0], a1 = pw[1], a2 = pw[2];
    float4 c0 = pi[0], c1 = pi[1], c2 = pi[2];
    l[0] = a0.x + c0.x; l[1] = a0.y + c0.y; l[2] = a0.z + c0.z; l[3] = a0.w + c0.w;
    l[4] = a1.x + c1.x; l[5] = a1.y + c1.y; l[6] = a1.z + c1.z; l[7] = a1.w + c1.w;
    l[8] = a2.x + c2.x; l[9] = a2.y + c2.y;
    float m = l[0];
#pragma unroll
    for (int k = 1; k < 10; ++k) m = fmaxf(m, l[k]);
    float s = 0.f;
#pragma unroll
    for (int k = 0; k < 10; ++k) { l[k] = (l[k] - m) * LOG2E; s += exp2f(l[k]); }
    float ls = log2f(s);
#pragma unroll
    for (int k = 0; k < 10; ++k) l[k] = (l[k] - ls) * LN2;
  }

#pragma unroll
  for (int k = 0; k < 10; ++k) sm[threadIdx.x * 10 + k] = l[k];
  __syncthreads();
  const f32x4* sm4 = (const f32x4*)sm;
  f32x4* ob = (f32x4*)(out + (size_t)blockIdx.x * 2560u);
  long lim4 = ((long)E * 10) >> 2;
  long base4 = (long)blockIdx.x * 640;
#pragma unroll
  for (int j = 0; j < 3; ++j) {
    int idx = j * 256 + threadIdx.x;
    if (idx < 640 && base4 + idx < lim4) ob[idx] = sm4[idx];
  }
}

// ---------------------------------------------------------------------------
// Fallbacks (only if d_ws too small or M%16 != 0).
// ---------------------------------------------------------------------------
__global__ __launch_bounds__(256) void enc_kernel_f32(
    const float* __restrict__ x0, const float* __restrict__ W0, const float* __restrict__ b0,
    const float* __restrict__ x1, const float* __restrict__ W1, const float* __restrict__ b1,
    float* __restrict__ out, int M)
{
  const int enc = blockIdx.y;
  const float* __restrict__ x = enc ? x1 : x0;
  const float* __restrict__ W = enc ? W1 : W0;
  const float* __restrict__ b = enc ? b1 : b0;
  float* __restrict__ o = out + (size_t)enc * (size_t)M * 64u;

  const int lane = threadIdx.x & 63;
  const int wid  = threadIdx.x >> 6;
  int row0 = __builtin_amdgcn_readfirstlane(blockIdx.x * 64 + wid * 16);
  const float* __restrict__ xrow = x + (size_t)row0 * 256u;

  float acc[16];
#pragma unroll
  for (int r = 0; r < 16; ++r) acc[r] = 0.f;

  if (row0 + 16 <= M) {
#pragma unroll 4
    for (int k = 0; k < 256; ++k) {
      float wv = W[k * 64 + lane];
#pragma unroll
      for (int r = 0; r < 16; ++r)
        acc[r] = fmaf(xrow[r * 256 + k], wv, acc[r]);
    }
    float bias = b[lane];
#pragma unroll
    for (int r = 0; r < 16; ++r) {
      float v = acc[r] + bias;
      v = fmaxf(v, 0.01f * v);
      o[(size_t)(row0 + r) * 64u + lane] = v;
    }
  } else if (row0 < M) {
    int nr = M - row0;
    for (int k = 0; k < 256; ++k) {
      float wv = W[k * 64 + lane];
      for (int r = 0; r < nr; ++r)
        acc[r] = fmaf(xrow[r * 256 + k], wv, acc[r]);
    }
    float bias = b[lane];
    for (int r = 0; r < nr; ++r) {
      float v = acc[r] + bias;
      v = fmaxf(v, 0.01f * v);
      o[(size_t)(row0 + r) * 64u + lane] = v;
    }
  }
}

__global__ __launch_bounds__(256) void edge_kernel_direct(
    const int* __restrict__ ei, const float* __restrict__ feats,
    const float* __restrict__ W_edge, const float* __restrict__ b_edge,
    float* __restrict__ out, int E, int M)
{
  __shared__ float sm[2560];
  long e = (long)blockIdx.x * 256 + threadIdx.x;
  float l[10];
#pragma unroll
  for (int k = 0; k < 10; ++k) l[k] = 0.f;

  if (e < E) {
    int e0 = ei[e];
    int e1 = ei[E + e];
#pragma unroll
    for (int k = 0; k < 10; ++k) l[k] = b_edge[k];
    const float4* fw = (const float4*)(feats + (size_t)e0 * 64u);
    const float4* fi = (const float4*)(feats + ((size_t)M + e1) * 64u);
#pragma unroll 4
    for (int n4 = 0; n4 < 16; ++n4) {
      float4 xv = fw[n4];
      const float* w = W_edge + n4 * 40;
#pragma unroll
      for (int k = 0; k < 10; ++k) l[k] = fmaf(xv.x, w[k],      l[k]);
#pragma unroll
      for (int k = 0; k < 10; ++k) l[k] = fmaf(xv.y, w[10 + k], l[k]);
#pragma unroll
      for (int k = 0; k < 10; ++k) l[k] = fmaf(xv.z, w[20 + k], l[k]);
#pragma unroll
      for (int k = 0; k < 10; ++k) l[k] = fmaf(xv.w, w[30 + k], l[k]);
    }
#pragma unroll 4
    for (int n4 = 0; n4 < 16; ++n4) {
      float4 xv = fi[n4];
      const float* w = W_edge + 640 + n4 * 40;
#pragma unroll
      for (int k = 0; k < 10; ++k) l[k] = fmaf(xv.x, w[k],      l[k]);
#pragma unroll
      for (int k = 0; k < 10; ++k) l[k] = fmaf(xv.y, w[10 + k], l[k]);
#pragma unroll
      for (int k = 0; k < 10; ++k) l[k] = fmaf(xv.z, w[20 + k], l[k]);
#pragma unroll
      for (int k = 0; k < 10; ++k) l[k] = fmaf(xv.w, w[30 + k], l[k]);
    }
    float m = l[0];
#pragma unroll
    for (int k = 1; k < 10; ++k) m = fmaxf(m, l[k]);
    float s = 0.f;
#pragma unroll
    for (int k = 0; k < 10; ++k) { l[k] = (l[k] - m) * LOG2E; s += exp2f(l[k]); }
    float ls = log2f(s);
#pragma unroll
    for (int k = 0; k < 10; ++k) l[k] = (l[k] - ls) * LN2;
  }

#pragma unroll
  for (int k = 0; k < 10; ++k) sm[threadIdx.x * 10 + k] = l[k];
  __syncthreads();
  const f32x4* sm4 = (const f32x4*)sm;
  f32x4* ob = (f32x4*)(out + (size_t)blockIdx.x * 2560u);
  long lim4 = ((long)E * 10) >> 2;
  long base4 = (long)blockIdx.x * 640;
#pragma unroll
  for (int j = 0; j < 3; ++j) {
    int idx = j * 256 + threadIdx.x;
    if (idx < 640 && base4 + idx < lim4) ob[idx] = sm4[idx];
  }
}

extern "C" void kernel_launch(void* const* d_in, const int* in_sizes, int n_in,
                              void* d_out, int out_size, void* d_ws, size_t ws_size,
                              hipStream_t stream)
{
  const float* x_w = (const float*)d_in[0];
  const float* x_i = (const float*)d_in[1];
  const int*   ei  = (const int*)d_in[2];
  const float* W_w = (const float*)d_in[3];
  const float* b_w = (const float*)d_in[4];
  const float* W_i = (const float*)d_in[5];
  const float* b_i = (const float*)d_in[6];
  const float* W_e = (const float*)d_in[7];
  const float* b_e = (const float*)d_in[8];
  float* out = (float*)d_out;

  const int M = in_sizes[0] / 256;   // 100000
  const int E = in_sizes[2] / 2;     // 2000000

  float* logout = out + (size_t)2 * (size_t)M * 64u;

  const size_t pw_bytes = (size_t)2 * (size_t)M * 16u * sizeof(float);
  const size_t ws_need  = pw_bytes + 65536;     // + wfrag table

  if (ws_size >= ws_need && (M % 16) == 0) {
    float*  ws    = (float*)d_ws;
    ushort* wfrag = (ushort*)((char*)d_ws + pw_bytes);

    wprep_kernel<<<16, 256, 0, stream>>>(W_w, W_i, wfrag);

    dim3 gA((unsigned)(M / 16), 2);  // one strip per block
    enc_simple_kernel<<<gA, 256, 0, stream>>>(x_w, b_w, x_i, b_i, wfrag, out, M);

    dim3 gB((M + 255) / 256, 2);
    proj_kernel<<<gB, 256, 0, stream>>>(out, W_e, b_e, ws, M);

    dim3 gC((unsigned)((E + 255) / 256));
    edge_kernel<<<gC, 256, 0, stream>>>(ei, ws, logout, E, M);
  } else {
    dim3 gA0((M + 63) / 64, 2);
    enc_kernel_f32<<<gA0, 256, 0, stream>>>(x_w, W_w, b_w, x_i, W_i, b_i, out, M);
    dim3 gC((unsigned)((E + 255) / 256));
    edge_kernel_direct<<<gC, 256, 0, stream>>>(ei, out, W_e, b_e, logout, E, M);
  }
}

// Round 12
// 117.183 us; speedup vs baseline: 1.2659x; 1.2659x over previous
//
#include <hip/hip_runtime.h>
#include <hip/hip_bf16.h>

#define LOG2E 1.4426950408889634f
#define LN2   0.6931471805599453f

typedef __attribute__((ext_vector_type(8))) short bf16x8;
typedef __attribute__((ext_vector_type(8))) unsigned short u16x8;
typedef __attribute__((ext_vector_type(4))) float f32x4;

static __device__ __forceinline__ short f2bf(float f) {
  __hip_bfloat16 h = __float2bfloat16(f);
  return *reinterpret_cast<short*>(&h);
}
static __device__ __forceinline__ ushort f2bfu(float f) {
  __hip_bfloat16 h = __float2bfloat16(f);
  return *reinterpret_cast<ushort*>(&h);
}
static __device__ __forceinline__ float bf2f(ushort u) {
  return __uint_as_float(((unsigned)u) << 16);
}

// ---------------------------------------------------------------------------
// wprep: pack W (f32 [256][64]) into per-lane MFMA B-fragments (bf16).
// wfrag[enc][f][lane][j], f=nsub*8+ks; elem = W[ks*32+(lane>>4)*8+j][nsub*16+(lane&15)]
// ---------------------------------------------------------------------------
__global__ __launch_bounds__(256) void wprep_kernel(
    const float* __restrict__ Ww, const float* __restrict__ Wi,
    ushort* __restrict__ wfrag)
{
  int id = blockIdx.x * 256 + threadIdx.x;       // 0..4095
  if (id >= 4096) return;
  int enc  = id >> 11;
  int f    = (id >> 6) & 31;
  int l    = id & 63;
  int nsub = f >> 3, ks = f & 7;
  const float* __restrict__ W = enc ? Wi : Ww;
  int n  = nsub * 16 + (l & 15);
  int k0 = ks * 32 + (l >> 4) * 8;
  ushort* dst = wfrag + ((size_t)(enc * 32 + f) * 64 + l) * 8;
#pragma unroll
  for (int j = 0; j < 8; ++j)
    dst[j] = (ushort)f2bf(W[(size_t)(k0 + j) * 64 + n]);
}

// ---------------------------------------------------------------------------
// enc_fused: R11's proven one-strip-per-block MFMA encoder + fused projection.
// Phase 1 (R11-identical): stage strip to LDS (swizzled), MFMA, bias+leaky,
// store xw. Phase 2 (new): activated tile -> LDS [16][68], 160-thread tail
// computes p[16][10] = tile @ W_edge_slice (+b_edge for enc0), packs bf16
// rows of 16 (32B), 32 threads store them. Eliminates proj_kernel entirely.
// Requires M%16==0.
// ---------------------------------------------------------------------------
__global__ __launch_bounds__(256) void enc_fused_kernel(
    const float* __restrict__ x0, const float* __restrict__ b0,
    const float* __restrict__ x1, const float* __restrict__ b1,
    const ushort* __restrict__ wfrag, const float* __restrict__ W_edge,
    const float* __restrict__ b_edge, float* __restrict__ out,
    ushort* __restrict__ pws, int M)
{
  __shared__ f32x4  xt[1024];                     // 16 KB staging
  __shared__ float  xwt[16 * 68];                 // 4.25 KB activated tile (padded)
  __shared__ float  w2[640];                      // W_edge slice (64x10)
  __shared__ ushort pwt[16 * 16];                 // 512 B packed bf16 rows

  const int enc = blockIdx.y;
  const float* __restrict__ x   = enc ? x1 : x0;
  const float* __restrict__ bia = enc ? b1 : b0;
  float* __restrict__ o = out + (size_t)enc * (size_t)M * 64u;

  const int t    = threadIdx.x;
  const int lane = t & 63;
  const int wid  = t >> 6;
  const int rsel = lane & 15;                     // A row / C col within tile
  const int kgrp = lane >> 4;                     // k-group / C row-group
  const int sw   = rsel & 7;
  const int strip = blockIdx.x;

  // W fragments + bias (L2-hot; overlaps x staging)
  bf16x8 wf[8];
#pragma unroll
  for (int ks = 0; ks < 8; ++ks)
    wf[ks] = *(const bf16x8*)(wfrag +
        ((size_t)((enc * 32 + wid * 8 + ks) * 64 + lane)) * 8);
  float bv = bia[wid * 16 + rsel];

  // W_edge slice to LDS (640 f32)
  for (int i = t; i < 640; i += 256) w2[i] = W_edge[enc * 640 + i];

  // stage strip: 4 passes x 256 threads x 16B, swizzled store
  const f32x4* __restrict__ xs = (const f32x4*)(x + (size_t)strip * 4096u);
#pragma unroll
  for (int p = 0; p < 4; ++p) {
    int idx = p * 256 + t;                        // 0..1023
    int row = idx >> 6, ch = idx & 63;
    xt[row * 64 + (ch ^ (row & 7))] = xs[idx];
  }
  __syncthreads();

  // fragments + MFMA
  f32x4 acc = f32x4{0.f, 0.f, 0.f, 0.f};
#pragma unroll
  for (int ks = 0; ks < 8; ++ks) {
    int c0 = ks * 8 + kgrp * 2;
    f32x4 lo = xt[rsel * 64 + ((c0    ) ^ sw)];
    f32x4 hi = xt[rsel * 64 + ((c0 + 1) ^ sw)];
    bf16x8 a;
    a[0] = f2bf(lo.x); a[1] = f2bf(lo.y); a[2] = f2bf(lo.z); a[3] = f2bf(lo.w);
    a[4] = f2bf(hi.x); a[5] = f2bf(hi.y); a[6] = f2bf(hi.z); a[7] = f2bf(hi.w);
    acc = __builtin_amdgcn_mfma_f32_16x16x32_bf16(a, wf[ks], acc, 0, 0, 0);
  }

  // epilogue: bias + leaky relu; store xw AND stash tile in LDS
  const int crow = strip * 16 + kgrp * 4;
  float* orow = o + (size_t)crow * 64u + wid * 16 + rsel;
#pragma unroll
  for (int r = 0; r < 4; ++r) {
    float v = acc[r] + bv;
    v = fmaxf(v, 0.01f * v);
    orow[r * 64] = v;
    xwt[(kgrp * 4 + r) * 68 + wid * 16 + rsel] = v;
  }
  __syncthreads();

  // fused projection tail: thread (r,c), r=0..15, c=0..9
  if (t < 160) {
    int r = t / 10, c = t - r * 10;
    float s = enc ? 0.f : b_edge[c];
    const float* xr = &xwt[r * 68];
#pragma unroll
    for (int i = 0; i < 64; ++i) s = fmaf(xr[i], w2[i * 10 + c], s);
    pwt[r * 16 + c] = f2bfu(s);
  }
  __syncthreads();

  // pack-out: 32 threads x 16B (rows contiguous -> 512B dense)
  if (t < 32) {
    int row = t >> 1, half = t & 1;
    u16x8* dst = (u16x8*)(pws + ((size_t)(enc * M + strip * 16 + row)) * 16u + half * 8);
    *dst = *(const u16x8*)&pwt[row * 16 + half * 8];
  }
}

// ---------------------------------------------------------------------------
// edge: logits[e] = pw_bf16[e0] + pi_bf16[e1] (bias pre-folded);
// 4 x 16B gathers/edge from the 6.4MB L2-resident tables; log_softmax;
// dense float4 stores via LDS transpose.
// ---------------------------------------------------------------------------
__global__ __launch_bounds__(256) void edge_kernel_bf16(
    const int* __restrict__ ei, const ushort* __restrict__ pws,
    float* __restrict__ out, int E, int M)
{
  __shared__ float sm[2560];
  long e = (long)blockIdx.x * 256 + threadIdx.x;
  float l[10];
#pragma unroll
  for (int k = 0; k < 10; ++k) l[k] = 0.f;

  if (e < E) {
    int e0 = ei[e];
    int e1 = ei[E + e];
    const u16x8* pw = (const u16x8*)(pws + (size_t)e0 * 16u);
    const u16x8* pi = (const u16x8*)(pws + ((size_t)M + e1) * 16u);
    u16x8 a0 = pw[0], a1 = pw[1];
    u16x8 c0 = pi[0], c1 = pi[1];
#pragma unroll
    for (int k = 0; k < 8; ++k) l[k] = bf2f(a0[k]) + bf2f(c0[k]);
    l[8] = bf2f(a1[0]) + bf2f(c1[0]);
    l[9] = bf2f(a1[1]) + bf2f(c1[1]);
    float m = l[0];
#pragma unroll
    for (int k = 1; k < 10; ++k) m = fmaxf(m, l[k]);
    float s = 0.f;
#pragma unroll
    for (int k = 0; k < 10; ++k) { l[k] = (l[k] - m) * LOG2E; s += exp2f(l[k]); }
    float ls = log2f(s);
#pragma unroll
    for (int k = 0; k < 10; ++k) l[k] = (l[k] - ls) * LN2;
  }

#pragma unroll
  for (int k = 0; k < 10; ++k) sm[threadIdx.x * 10 + k] = l[k];
  __syncthreads();
  const f32x4* sm4 = (const f32x4*)sm;
  f32x4* ob = (f32x4*)(out + (size_t)blockIdx.x * 2560u);
  long lim4 = ((long)E * 10) >> 2;
  long base4 = (long)blockIdx.x * 640;
#pragma unroll
  for (int j = 0; j < 3; ++j) {
    int idx = j * 256 + threadIdx.x;
    if (idx < 640 && base4 + idx < lim4) ob[idx] = sm4[idx];
  }
}

// ---------------------------------------------------------------------------
// Fallbacks (only if d_ws too small or M%16 != 0).
// ---------------------------------------------------------------------------
__global__ __launch_bounds__(256) void enc_kernel_f32(
    const float* __restrict__ x0, const float* __restrict__ W0, const float* __restrict__ b0,
    const float* __restrict__ x1, const float* __restrict__ W1, const float* __restrict__ b1,
    float* __restrict__ out, int M)
{
  const int enc = blockIdx.y;
  const float* __restrict__ x = enc ? x1 : x0;
  const float* __restrict__ W = enc ? W1 : W0;
  const float* __restrict__ b = enc ? b1 : b0;
  float* __restrict__ o = out + (size_t)enc * (size_t)M * 64u;

  const int lane = threadIdx.x & 63;
  const int wid  = threadIdx.x >> 6;
  int row0 = __builtin_amdgcn_readfirstlane(blockIdx.x * 64 + wid * 16);
  const float* __restrict__ xrow = x + (size_t)row0 * 256u;

  float acc[16];
#pragma unroll
  for (int r = 0; r < 16; ++r) acc[r] = 0.f;

  if (row0 + 16 <= M) {
#pragma unroll 4
    for (int k = 0; k < 256; ++k) {
      float wv = W[k * 64 + lane];
#pragma unroll
      for (int r = 0; r < 16; ++r)
        acc[r] = fmaf(xrow[r * 256 + k], wv, acc[r]);
    }
    float bias = b[lane];
#pragma unroll
    for (int r = 0; r < 16; ++r) {
      float v = acc[r] + bias;
      v = fmaxf(v, 0.01f * v);
      o[(size_t)(row0 + r) * 64u + lane] = v;
    }
  } else if (row0 < M) {
    int nr = M - row0;
    for (int k = 0; k < 256; ++k) {
      float wv = W[k * 64 + lane];
      for (int r = 0; r < nr; ++r)
        acc[r] = fmaf(xrow[r * 256 + k], wv, acc[r]);
    }
    float bias = b[lane];
    for (int r = 0; r < nr; ++r) {
      float v = acc[r] + bias;
      v = fmaxf(v, 0.01f * v);
      o[(size_t)(row0 + r) * 64u + lane] = v;
    }
  }
}

__global__ __launch_bounds__(256) void edge_kernel_direct(
    const int* __restrict__ ei, const float* __restrict__ feats,
    const float* __restrict__ W_edge, const float* __restrict__ b_edge,
    float* __restrict__ out, int E, int M)
{
  __shared__ float sm[2560];
  long e = (long)blockIdx.x * 256 + threadIdx.x;
  float l[10];
#pragma unroll
  for (int k = 0; k < 10; ++k) l[k] = 0.f;

  if (e < E) {
    int e0 = ei[e];
    int e1 = ei[E + e];
#pragma unroll
    for (int k = 0; k < 10; ++k) l[k] = b_edge[k];
    const float4* fw = (const float4*)(feats + (size_t)e0 * 64u);
    const float4* fi = (const float4*)(feats + ((size_t)M + e1) * 64u);
#pragma unroll 4
    for (int n4 = 0; n4 < 16; ++n4) {
      float4 xv = fw[n4];
      const float* w = W_edge + n4 * 40;
#pragma unroll
      for (int k = 0; k < 10; ++k) l[k] = fmaf(xv.x, w[k],      l[k]);
#pragma unroll
      for (int k = 0; k < 10; ++k) l[k] = fmaf(xv.y, w[10 + k], l[k]);
#pragma unroll
      for (int k = 0; k < 10; ++k) l[k] = fmaf(xv.z, w[20 + k], l[k]);
#pragma unroll
      for (int k = 0; k < 10; ++k) l[k] = fmaf(xv.w, w[30 + k], l[k]);
    }
#pragma unroll 4
    for (int n4 = 0; n4 < 16; ++n4) {
      float4 xv = fi[n4];
      const float* w = W_edge + 640 + n4 * 40;
#pragma unroll
      for (int k = 0; k < 10; ++k) l[k] = fmaf(xv.x, w[k],      l[k]);
#pragma unroll
      for (int k = 0; k < 10; ++k) l[k] = fmaf(xv.y, w[10 + k], l[k]);
#pragma unroll
      for (int k = 0; k < 10; ++k) l[k] = fmaf(xv.z, w[20 + k], l[k]);
#pragma unroll
      for (int k = 0; k < 10; ++k) l[k] = fmaf(xv.w, w[30 + k], l[k]);
    }
    float m = l[0];
#pragma unroll
    for (int k = 1; k < 10; ++k) m = fmaxf(m, l[k]);
    float s = 0.f;
#pragma unroll
    for (int k = 0; k < 10; ++k) { l[k] = (l[k] - m) * LOG2E; s += exp2f(l[k]); }
    float ls = log2f(s);
#pragma unroll
    for (int k = 0; k < 10; ++k) l[k] = (l[k] - ls) * LN2;
  }

#pragma unroll
  for (int k = 0; k < 10; ++k) sm[threadIdx.x * 10 + k] = l[k];
  __syncthreads();
  const f32x4* sm4 = (const f32x4*)sm;
  f32x4* ob = (f32x4*)(out + (size_t)blockIdx.x * 2560u);
  long lim4 = ((long)E * 10) >> 2;
  long base4 = (long)blockIdx.x * 640;
#pragma unroll
  for (int j = 0; j < 3; ++j) {
    int idx = j * 256 + threadIdx.x;
    if (idx < 640 && base4 + idx < lim4) ob[idx] = sm4[idx];
  }
}

extern "C" void kernel_launch(void* const* d_in, const int* in_sizes, int n_in,
                              void* d_out, int out_size, void* d_ws, size_t ws_size,
                              hipStream_t stream)
{
  const float* x_w = (const float*)d_in[0];
  const float* x_i = (const float*)d_in[1];
  const int*   ei  = (const int*)d_in[2];
  const float* W_w = (const float*)d_in[3];
  const float* b_w = (const float*)d_in[4];
  const float* W_i = (const float*)d_in[5];
  const float* b_i = (const float*)d_in[6];
  const float* W_e = (const float*)d_in[7];
  const float* b_e = (const float*)d_in[8];
  float* out = (float*)d_out;

  const int M = in_sizes[0] / 256;   // 100000
  const int E = in_sizes[2] / 2;     // 2000000

  float* logout = out + (size_t)2 * (size_t)M * 64u;

  const size_t pw_bytes = (size_t)2 * (size_t)M * 16u * sizeof(ushort);  // 6.4 MB
  const size_t ws_need  = pw_bytes + 65536;     // + wfrag table

  if (ws_size >= ws_need && (M % 16) == 0) {
    ushort* pws   = (ushort*)d_ws;
    ushort* wfrag = (ushort*)((char*)d_ws + pw_bytes);

    wprep_kernel<<<16, 256, 0, stream>>>(W_w, W_i, wfrag);

    dim3 gA((unsigned)(M / 16), 2);  // one strip per block
    enc_fused_kernel<<<gA, 256, 0, stream>>>(x_w, b_w, x_i, b_i, wfrag,
                                             W_e, b_e, out, pws, M);

    dim3 gC((unsigned)((E + 255) / 256));
    edge_kernel_bf16<<<gC, 256, 0, stream>>>(ei, pws, logout, E, M);
  } else {
    dim3 gA0((M + 63) / 64, 2);
    enc_kernel_f32<<<gA0, 256, 0, stream>>>(x_w, W_w, b_w, x_i, W_i, b_i, out, M);
    dim3 gC((unsigned)((E + 255) / 256));
    edge_kernel_direct<<<gC, 256, 0, stream>>>(ei, out, W_e, b_e, logout, E, M);
  }
}